// Round 6
// baseline (317.458 us; speedup 1.0000x reference)
//
#include <hip/hip_runtime.h>

#define B_   8
#define C_   96
#define H_   160
#define W_   320
#define ND   9
#define NDD  81
#define TH   16
#define TW   16
#define KC   8
#define NCH  12
// Per-buffer LDS layout (dwords):
//   f1: 8 planes x 256  (16x16, stride 16 -> read addr = 4*lane, conflict-free)
//   f2: 8 planes x 768  (24 rows x 32 dw; cols 0..5 payload, 6..7 pad;
//                        16B-column XOR-swizzled by row&7)
#define F1PLANE 256
#define F2PLANE 768
#define F2OFF   (KC*F1PLANE)              // 2048
#define BUFW    (KC*(F1PLANE+F2PLANE))    // 8192 dw = 32768 B
#define LDSWORDS (2*BUFW)                 // 65536 B -> 2 blocks/CU

#define AS1 __attribute__((address_space(1)))
#define AS3 __attribute__((address_space(3)))

__device__ __forceinline__ void gld16(const float* gp, const float* lp) {
    // HBM -> LDS direct; LDS dest = uniform base + lane*16
    __builtin_amdgcn_global_load_lds((const AS1 float*)gp,
                                     (AS3 float*)(unsigned long long)lp, 16, 0, 0);
}

__global__ __launch_bounds__(576, 8)      // min 8 waves/EU -> VGPR budget 64
void corr_kernel(const float* __restrict__ f1g,
                 const float* __restrict__ f2g,
                 float* __restrict__ out)
{
    __shared__ float lds[LDSWORDS];

    const int tid  = threadIdx.x;
    const int wave = tid >> 6;            // dh 0..8
    const int lane = tid & 63;
    const int row  = lane >> 2;           // 0..15
    const int m    = lane & 3;
    const int colb = m << 2;              // 0,4,8,12

    // XCD swizzle: 1600 blocks = 8 XCDs x 200; XCD k owns batch k.
    const int bid  = blockIdx.x;
    const int ebid = (bid & 7) * 200 + (bid >> 3);
    const int b    = ebid / 200;
    const int rr   = ebid - b * 200;
    const int by   = rr / 20;
    const int bx   = rr - by * 20;
    const int x0 = bx * TW, y0 = by * TH;
    const int HWi  = H_ * W_;

    const float* f1b = f1g + (size_t)b * C_ * HWi;
    const float* f2b = f2g + (size_t)b * C_ * HWi;

    // ---- staging descriptors (per-lane, prologue only) ----
    // f1: lane i -> lds slot 4i <-> (r=i>>2, c=4(i&3)); always in-bounds
    const int f1so = (y0 + row) * W_ + x0 + colb;
    // f2: lane i stages 16B to plane slot (group*256 + 4i):
    //   row-in-group rr8 = i>>3, physical col = i&7, logical col = (i&7)^rr8
    const int  rr8 = lane >> 3;
    const int  cbl = (lane & 7) ^ rr8;                 // logical 16B column
    const int  fx  = x0 - 4 + (cbl << 2);
    const bool xok = (cbl <= 5) & (fx >= 0) & (fx <= W_ - 4);
    const int  gy0 = y0 - 4 + rr8;                     // group 0 row
    const bool ok0 = xok & (gy0 >= 0);                 // gy0 < H always (y0<=144)
    const bool ok1 = xok;                              // gy0+8 in [4,167]... check:
    const bool ok1b = ok1 & (gy0 + 8 < H_);
    const bool ok2 = xok & (gy0 + 16 < H_);
    const int  off0 = gy0 * W_ + fx;                   // groups 1/2 = +8W,+16W (uniform)

    // ---- compute-side swizzled LDS read offsets (dwords) ----
    const int rW = row + wave;                         // f2 row 0..23
    const int sw = rW & 7;
    const int o0 = rW * 32 + (((m + 0) ^ sw) << 2);
    const int o1 = rW * 32 + (((m + 1) ^ sw) << 2);
    const int o2 = rW * 32 + (((m + 2) ^ sw) << 2);
    const int f1ro = lane << 2;

    // staging: wave w<8 -> f1 plane w (1 gld16) + f2 plane w (3 gld16); wave 8 idles
    auto stage = [&](int cb, int bufb) {
        if (wave < 8) {
            const int co = (cb + wave) * HWi;
            gld16(f1b + co + f1so, &lds[bufb + wave * F1PLANE]);
            const float* p = f2b + co + off0;
            const float* l = &lds[bufb + F2OFF + wave * F2PLANE];
            if (ok0)  gld16(p,             l);
            if (ok1b) gld16(p + 8  * W_,   l + 256);
            if (ok2)  gld16(p + 16 * W_,   l + 512);
        }
    };

    // ---- named accumulators ----
    float4 acc0, acc1, acc2, acc3, acc4, acc5, acc6, acc7, acc8;
    acc0 = acc1 = acc2 = acc3 = acc4 = acc5 = acc6 = acc7 = acc8 = make_float4(0.f, 0.f, 0.f, 0.f);

#define STEPD(A, P, e0, e1, e2, e3)                             \
        A.x = fmaf(P.x, e0, A.x);                               \
        A.y = fmaf(P.y, e1, A.y);                               \
        A.z = fmaf(P.z, e2, A.z);                               \
        A.w = fmaf(P.w, e3, A.w);

#define COMPC(c, RB) {                                                              \
        const float4 P  = *(const float4*)&lds[(RB) + c * F1PLANE + f1ro];          \
        const float4 q0 = *(const float4*)&lds[(RB) + F2OFF + c * F2PLANE + o0];    \
        const float4 q1 = *(const float4*)&lds[(RB) + F2OFF + c * F2PLANE + o1];    \
        const float4 q2 = *(const float4*)&lds[(RB) + F2OFF + c * F2PLANE + o2];    \
        STEPD(acc0, P, q0.x, q0.y, q0.z, q0.w)                                      \
        STEPD(acc1, P, q0.y, q0.z, q0.w, q1.x)                                      \
        STEPD(acc2, P, q0.z, q0.w, q1.x, q1.y)                                      \
        STEPD(acc3, P, q0.w, q1.x, q1.y, q1.z)                                      \
        STEPD(acc4, P, q1.x, q1.y, q1.z, q1.w)                                      \
        STEPD(acc5, P, q1.y, q1.z, q1.w, q2.x)                                      \
        STEPD(acc6, P, q1.z, q1.w, q2.x, q2.y)                                      \
        STEPD(acc7, P, q1.w, q2.x, q2.y, q2.z)                                      \
        STEPD(acc8, P, q2.x, q2.y, q2.z, q2.w)                                      \
    }
#define CHUNK(RB) COMPC(0,RB) COMPC(1,RB) COMPC(2,RB) COMPC(3,RB) \
                  COMPC(4,RB) COMPC(5,RB) COMPC(6,RB) COMPC(7,RB)

    // ---- one-time LDS zero: exec-masked (OOB/pad) slots are never DMA'd,
    //      and every payload slot is rewritten every chunk -> zeros persist ----
    for (int t = tid; t < LDSWORDS; t += 576) lds[t] = 0.f;
    __syncthreads();
    stage(0, 0);                           // chunk 0 -> buf 0

#pragma unroll 1
    for (int kk = 0; kk < NCH / 2; ++kk) {
        __syncthreads();                   // own vmcnt drained; chunk 2kk in LDS
        stage((2 * kk + 1) * KC, BUFW);    // prefetch odd chunk -> buf 1
        CHUNK(0)
        __syncthreads();
        if (kk < NCH / 2 - 1) stage((2 * kk + 2) * KC, 0);  // even chunk -> buf 0
        CHUNK(BUFW)
    }

    // ---- epilogue: out[b, wave*9+d, y0+row, x0+colb .. +3] ----
    const int gy = y0 + row;
    const int gx = x0 + colb;
#define STORED(d) {                                                                   \
        float* op_ = out + (size_t)((b * NDD + wave * ND + d) * H_ + gy) * W_ + gx;   \
        *(float4*)op_ = acc##d; }
    STORED(0) STORED(1) STORED(2) STORED(3) STORED(4)
    STORED(5) STORED(6) STORED(7) STORED(8)
}

extern "C" void kernel_launch(void* const* d_in, const int* in_sizes, int n_in,
                              void* d_out, int out_size, void* d_ws, size_t ws_size,
                              hipStream_t stream)
{
    const float* f1 = (const float*)d_in[0];
    const float* f2 = (const float*)d_in[1];
    float* out = (float*)d_out;
    corr_kernel<<<dim3(1600), 576, 0, stream>>>(f1, f2, out);
}

// Round 7
// 219.602 us; speedup vs baseline: 1.4456x; 1.4456x over previous
//
#include <hip/hip_runtime.h>

#define B_   8
#define C_   96
#define H_   160
#define W_   320
#define ND   9
#define NDD  81
#define TH   16
#define TW   16
#define KC   4                 // channels per chunk
#define NCH  24                // 96/4 chunks
#define F2ROWS 18              // halo rows per dh-group: 16 + 3 - 1 + ... = [y0+3g-4, y0+3g+13]
// Per-buffer LDS (dwords):
//   f1: 4 planes x 256 (16x16 stride16; read addr 4*lane -> conflict-free)
//   f2: 4 planes x 576 (18 rows x 32 dw; cols 0..5 payload, 6..7 pad;
//                       16B-column XOR-swizzled by row&7)
#define F1PLANE 256
#define F2PLANE (F2ROWS*32)               // 576
#define F2OFF   (KC*F1PLANE)              // 1024
#define BUFW    (KC*(F1PLANE+F2PLANE))    // 3328 dw = 13312 B
#define LDSWORDS (2*BUFW)                 // 26624 B -> 6 blocks/CU

#define AS1 __attribute__((address_space(1)))
#define AS3 __attribute__((address_space(3)))

__device__ __forceinline__ void gld16(const float* gp, const float* lp) {
    __builtin_amdgcn_global_load_lds((const AS1 float*)gp,
                                     (AS3 float*)(unsigned long long)lp, 16, 0, 0);
}
__device__ __forceinline__ void gld4(const float* gp, const float* lp) {
    __builtin_amdgcn_global_load_lds((const AS1 float*)gp,
                                     (AS3 float*)(unsigned long long)lp, 4, 0, 0);
}

__global__ __launch_bounds__(192, 6)      // VGPR cap 512/6 = 85 (proven no-spill region)
void corr_kernel(const float* __restrict__ f1g,
                 const float* __restrict__ f2g,
                 float* __restrict__ out)
{
    __shared__ float lds[LDSWORDS];

    const int tid  = threadIdx.x;
    const int wave = tid >> 6;            // 0..2 within dh-group
    const int lane = tid & 63;
    const int row  = lane >> 2;           // 0..15
    const int m    = lane & 3;
    const int colb = m << 2;              // 0,4,8,12

    // XCD swizzle: 4800 blocks = 8 XCDs x 600. XCD owns batch b; within it,
    // the 3 dh-groups of each tile are dispatch-adjacent (L2 reuse of f1+halo).
    const int bid  = blockIdx.x;
    const int ebid = (bid & 7) * 600 + (bid >> 3);
    const int b    = ebid / 600;
    const int t6   = ebid - b * 600;
    const int g    = t6 % 3;              // dh-group: dh = 3g + wave
    const int tile = t6 / 3;              // 0..199
    const int by   = tile / 20;
    const int bx   = tile - by * 20;
    const int x0 = bx * TW, y0 = by * TH;
    const int HWi  = H_ * W_;
    const int r0   = y0 + 3 * g - 4;      // first f2 halo row (global)

    const float* f1b = f1g + (size_t)b * C_ * HWi;
    const float* f2b = f2g + (size_t)b * C_ * HWi;

    // ---- staging descriptors (per-lane, prologue only) ----
    // f1: lane i -> lds dw 4i <-> (r=i>>2, c=4(i&3)) == (row, colb). In-bounds.
    const int f1so = (y0 + row) * W_ + x0 + colb;
    // f2 gld16 groups (8 rows x 32 dw each): lane -> row rr8=lane>>3, phys 16Bcol
    // p=lane&7, logical col l = p ^ rr8 (same for both groups since (row&7) repeats).
    const int  rr8 = lane >> 3;
    const int  lcl = (lane & 7) ^ rr8;
    const int  fx  = x0 - 4 + (lcl << 2);
    const bool xok = (lcl <= 5) & (fx >= 0) & (fx <= W_ - 4);
    const int  gy0 = r0 + rr8;                         // group-0 global row
    const bool ok0 = xok & (gy0 >= 0) & (gy0 < H_);
    const bool ok1 = xok & (gy0 + 8 < H_);             // gy0+8 >= 4 always
    const int  off0 = gy0 * W_ + fx;
    // f2 tail (rows 16..17, 64 dw): lane -> row 16+(lane>>5), dword col lane&31
    const int  rT  = r0 + 16 + (lane >> 5);
    const int  lT  = ((lane >> 2) & 7) ^ (lane >> 5);  // logical 16B col
    const int  xT  = x0 - 4 + (lT << 2) + (lane & 3);
    const bool okT = (lT <= 5) & (xT >= 0) & (xT < W_) & (rT < H_);  // rT>=12 always
    const int  offT = rT * W_ + xT;

    // ---- compute-side swizzled LDS read offsets (dwords) ----
    const int rW = row + wave;                         // f2 lds row 0..17
    const int sw = rW & 7;
    const int o0 = rW * 32 + (((m + 0) ^ sw) << 2);
    const int o1 = rW * 32 + (((m + 1) ^ sw) << 2);
    const int o2 = rW * 32 + (((m + 2) ^ sw) << 2);
    const int f1ro = lane << 2;

    // staging: 16 segments/chunk (4 ch x {f1, f2 rows0-7, f2 rows8-15, f2 tail}),
    // round-robined across the 3 waves
    auto stage = [&](int cb, int bufb) {
        for (int s = wave; s < 16; s += 3) {
            const int ch = s >> 2;
            const int co = (cb + ch) * HWi;
            const int part = s & 3;
            if (part == 0) {
                gld16(f1b + co + f1so, &lds[bufb + ch * F1PLANE]);
            } else if (part == 1) {
                if (ok0) gld16(f2b + co + off0, &lds[bufb + F2OFF + ch * F2PLANE]);
            } else if (part == 2) {
                if (ok1) gld16(f2b + co + off0 + 8 * W_, &lds[bufb + F2OFF + ch * F2PLANE + 256]);
            } else {
                if (okT) gld4(f2b + co + offT, &lds[bufb + F2OFF + ch * F2PLANE + 512]);
            }
        }
    };

    // ---- named accumulators: 9 dw x 4 px ----
    float4 acc0, acc1, acc2, acc3, acc4, acc5, acc6, acc7, acc8;
    acc0 = acc1 = acc2 = acc3 = acc4 = acc5 = acc6 = acc7 = acc8 = make_float4(0.f, 0.f, 0.f, 0.f);

#define STEPD(A, P, e0, e1, e2, e3)                             \
        A.x = fmaf(P.x, e0, A.x);                               \
        A.y = fmaf(P.y, e1, A.y);                               \
        A.z = fmaf(P.z, e2, A.z);                               \
        A.w = fmaf(P.w, e3, A.w);

#define COMPC(c, RB) {                                                              \
        const float4 P  = *(const float4*)&lds[(RB) + c * F1PLANE + f1ro];          \
        const float4 q0 = *(const float4*)&lds[(RB) + F2OFF + c * F2PLANE + o0];    \
        const float4 q1 = *(const float4*)&lds[(RB) + F2OFF + c * F2PLANE + o1];    \
        const float4 q2 = *(const float4*)&lds[(RB) + F2OFF + c * F2PLANE + o2];    \
        STEPD(acc0, P, q0.x, q0.y, q0.z, q0.w)                                      \
        STEPD(acc1, P, q0.y, q0.z, q0.w, q1.x)                                      \
        STEPD(acc2, P, q0.z, q0.w, q1.x, q1.y)                                      \
        STEPD(acc3, P, q0.w, q1.x, q1.y, q1.z)                                      \
        STEPD(acc4, P, q1.x, q1.y, q1.z, q1.w)                                      \
        STEPD(acc5, P, q1.y, q1.z, q1.w, q2.x)                                      \
        STEPD(acc6, P, q1.z, q1.w, q2.x, q2.y)                                      \
        STEPD(acc7, P, q1.w, q2.x, q2.y, q2.z)                                      \
        STEPD(acc8, P, q2.x, q2.y, q2.z, q2.w)                                      \
    }
#define CHUNK(RB) COMPC(0,RB) COMPC(1,RB) COMPC(2,RB) COMPC(3,RB)

    // one-time zero: OOB/pad slots are never DMA'd and payload slots are
    // rewritten every chunk -> zeros persist for masked regions
    for (int t = tid; t < LDSWORDS; t += 192) lds[t] = 0.f;
    __syncthreads();
    stage(0, 0);                           // chunk 0 -> buf 0

#pragma unroll 1
    for (int kk = 0; kk < NCH / 2; ++kk) {
        __syncthreads();                   // drains chunk 2kk DMA (vmcnt+lgkm)
        stage((2 * kk + 1) * KC, BUFW);    // prefetch odd chunk -> buf 1
        CHUNK(0)
        __syncthreads();                   // drains odd chunk
        if (kk < NCH / 2 - 1) stage((2 * kk + 2) * KC, 0);
        CHUNK(BUFW)
    }

    // ---- epilogue: dh = 3g + wave; out[b, dh*9+d, y0+row, x0+colb..+3] ----
    const int dh = 3 * g + wave;
    const int gy = y0 + row;
    const int gx = x0 + colb;
#define STORED(d) {                                                                   \
        float* op_ = out + (size_t)((b * NDD + dh * ND + d) * H_ + gy) * W_ + gx;     \
        *(float4*)op_ = acc##d; }
    STORED(0) STORED(1) STORED(2) STORED(3) STORED(4)
    STORED(5) STORED(6) STORED(7) STORED(8)
}

extern "C" void kernel_launch(void* const* d_in, const int* in_sizes, int n_in,
                              void* d_out, int out_size, void* d_ws, size_t ws_size,
                              hipStream_t stream)
{
    const float* f1 = (const float*)d_in[0];
    const float* f2 = (const float*)d_in[1];
    float* out = (float*)d_out;
    corr_kernel<<<dim3(4800), 192, 0, stream>>>(f1, f2, out);
}